// Round 12
// baseline (36.149 us; speedup 1.0000x reference)
//
#include <hip/hip_runtime.h>
#include <math.h>

// B=1, N=4096 queries, F=4096 faces (fixed by reference setup_inputs).
#define N_Q 4096
#define N_F 4096
#define WAVES 4                 // waves per block (256 threads)
#define QPW 2                   // queries per wave (exclusively owned)
#define QPB (WAVES * QPW)       // 8 queries per block
#define NBLK (N_Q / QPB)        // 512 blocks = 2/CU = 8 waves/CU
#define TF 256                  // faces per LDS tile
#define NT (N_F / TF)           // 16 tiles
#define PAIRS (TF / 2)          // 128 face-pairs per tile
#define PDW 20                  // dwords per pair entry (18 data + 2 pad, 16B-aligned)
#define TILE_DW (PAIRS * PDW)   // 2560 dwords per buffer
#define INV_2PI 0.15915494309189535f

typedef __attribute__((ext_vector_type(2))) float f32x2;
typedef __attribute__((ext_vector_type(4))) float f32x4;

static __device__ __forceinline__ f32x2 fma2(f32x2 a, f32x2 b, f32x2 c) {
    return __builtin_elementwise_fma(a, b, c);   // v_pk_fma_f32
}
static __device__ __forceinline__ f32x2 splat(float x) { return (f32x2){x, x}; }
static __device__ __forceinline__ f32x2 lo2(f32x4 v) { return __builtin_shufflevector(v, v, 0, 1); }
static __device__ __forceinline__ f32x2 hi2(f32x4 v) { return __builtin_shufflevector(v, v, 2, 3); }

// Packed fast atan2 for two (y,x) pairs. Max err ~1e-5 rad.
static __device__ __forceinline__ f32x2 fast_atan2_2(f32x2 y, f32x2 x) {
    const float pi   = 3.14159265358979f;
    const float pi_2 = 1.57079632679490f;
    f32x2 ax = __builtin_elementwise_abs(x);
    f32x2 ay = __builtin_elementwise_abs(y);
    f32x2 mx = __builtin_elementwise_max(ax, ay);
    f32x2 mn = __builtin_elementwise_min(ax, ay);
    mx = __builtin_elementwise_max(mx, splat(1e-30f));   // 0/0 -> 0, no NaN
    f32x2 rc = { __builtin_amdgcn_rcpf(mx.x), __builtin_amdgcn_rcpf(mx.y) };
    f32x2 t = mn * rc;                                   // in [0,1]
    f32x2 s = t * t;
    f32x2 p = splat(-0.0117212f);
    p = fma2(p, s, splat( 0.05265332f));
    p = fma2(p, s, splat(-0.11643287f));
    p = fma2(p, s, splat( 0.19354346f));
    p = fma2(p, s, splat(-0.33262347f));
    p = fma2(p, s, splat( 0.99997726f));
    f32x2 r = p * t;                                     // atan(t) on [0, pi/4]
    float r0 = (ay.x > ax.x) ? (pi_2 - r.x) : r.x;
    float r1 = (ay.y > ax.y) ? (pi_2 - r.y) : r.y;
    r0 = (x.x < 0.0f) ? (pi - r0) : r0;
    r1 = (x.y < 0.0f) ? (pi - r1) : r1;
    return (f32x2){ copysignf(r0, y.x), copysignf(r1, y.y) };
}

// Solid-angle terms for one query vs TWO faces (packed), direct formula.
// Face comps arrive as 9 f32x2 = {val(face even), val(face odd)}.
static __device__ __forceinline__ f32x2 pair2_direct(
    f32x2 mqx, f32x2 mqy, f32x2 mqz,
    f32x2 Ax, f32x2 Ay, f32x2 Az,
    f32x2 Bx, f32x2 By, f32x2 Bz,
    f32x2 Cx, f32x2 Cy, f32x2 Cz)
{
    const f32x2 ax = Ax + mqx, ay = Ay + mqy, az = Az + mqz;
    const f32x2 bx = Bx + mqx, by = By + mqy, bz = Bz + mqz;
    const f32x2 cx = Cx + mqx, cy = Cy + mqy, cz = Cz + mqz;

    // u = b x c ; det = a . u
    const f32x2 ux = fma2(by, cz, -(bz * cy));
    const f32x2 uy = fma2(bz, cx, -(bx * cz));
    const f32x2 uz = fma2(bx, cy, -(by * cx));
    const f32x2 det = fma2(ax, ux, fma2(ay, uy, az * uz));

    const f32x2 ra = fma2(ax, ax, fma2(ay, ay, az * az));
    const f32x2 rb = fma2(bx, bx, fma2(by, by, bz * bz));
    const f32x2 rc = fma2(cx, cx, fma2(cy, cy, cz * cz));
    const f32x2 na = { __builtin_amdgcn_sqrtf(ra.x), __builtin_amdgcn_sqrtf(ra.y) };
    const f32x2 nb = { __builtin_amdgcn_sqrtf(rb.x), __builtin_amdgcn_sqrtf(rb.y) };
    const f32x2 nc = { __builtin_amdgcn_sqrtf(rc.x), __builtin_amdgcn_sqrtf(rc.y) };

    const f32x2 ab = fma2(ax, bx, fma2(ay, by, az * bz));
    const f32x2 bc = fma2(bx, cx, fma2(by, cy, bz * cz));
    const f32x2 ac = fma2(ax, cx, fma2(ay, cy, az * cz));

    const f32x2 den = fma2(na * nb, nc, fma2(bc, na, fma2(ac, nb, ab * nc)));
    return fast_atan2_2(det, den);
}

// One wave owns QPW queries over ALL faces: no atomics, no memset, one
// dispatch. Faces stream through double-buffered LDS in pair-interleaved
// layout so ds_read_b128 yields ready f32x2 pk operands (zero splat movs).
__global__ __launch_bounds__(256) void winding_kernel(
    const float* __restrict__ qp,   // [N_Q][3]
    const float* __restrict__ fc,   // [N_F][9]
    float* __restrict__ out)        // [N_Q]
{
    __shared__ __align__(16) float lds[2 * TILE_DW];

    const int tid  = threadIdx.x;
    const int lane = tid & 63;
    const int wid  = tid >> 6;
    const int qbase = blockIdx.x * QPB + wid * QPW;

    // Hoisted negated queries, duplicated for pk ops.
    const f32x2 mqx0 = splat(-qp[(qbase+0)*3+0]);
    const f32x2 mqy0 = splat(-qp[(qbase+0)*3+1]);
    const f32x2 mqz0 = splat(-qp[(qbase+0)*3+2]);
    const f32x2 mqx1 = splat(-qp[(qbase+1)*3+0]);
    const f32x2 mqy1 = splat(-qp[(qbase+1)*3+1]);
    const f32x2 mqz1 = splat(-qp[(qbase+1)*3+2]);

    // Stage tile 0 into buffer 0.
    // Pair-interleaved layout: dword d of a buffer: pr=d/PDW, k=d%PDW;
    // k<18: comp c=k>>1 of face (tile*TF + pr*2 + (k&1)).
    #pragma unroll
    for (int k = 0; k < TILE_DW / 256; ++k) {
        const int d  = tid + k * 256;
        const int pr = d / PDW, k2 = d - pr * PDW;
        if (k2 < 18) {
            const int face = pr * 2 + (k2 & 1);
            lds[d] = fc[(size_t)face * 9 + (k2 >> 1)];
        }
    }
    __syncthreads();

    f32x2 acc0 = {0.0f, 0.0f}, acc1 = {0.0f, 0.0f};

    for (int t = 0; t < NT; ++t) {
        const int cur = t & 1;
        const float* buf = lds + cur * TILE_DW;

        // Issue next tile's global loads early (consumed after compute).
        float stg[TILE_DW / 256];
        if (t + 1 < NT) {
            #pragma unroll
            for (int k = 0; k < TILE_DW / 256; ++k) {
                const int d  = tid + k * 256;
                const int pr = d / PDW, k2 = d - pr * PDW;
                stg[k] = (k2 < 18)
                    ? fc[(size_t)((t + 1) * TF + pr * 2 + (k2 & 1)) * 9 + (k2 >> 1)]
                    : 0.0f;
            }
        }

        // Compute: lane handles face-pairs (lane) and (lane+64).
        #pragma unroll
        for (int g = 0; g < 2; ++g) {
            const f32x4* pb = (const f32x4*)(buf + (lane + g * 64) * PDW);
            const f32x4 r0 = pb[0], r1 = pb[1], r2 = pb[2], r3 = pb[3], r4 = pb[4];
            const f32x2 Ax = lo2(r0), Ay = hi2(r0);
            const f32x2 Az = lo2(r1), Bx = hi2(r1);
            const f32x2 By = lo2(r2), Bz = hi2(r2);
            const f32x2 Cx = lo2(r3), Cy = hi2(r3);
            const f32x2 Cz = lo2(r4);
            acc0 += pair2_direct(mqx0, mqy0, mqz0, Ax,Ay,Az, Bx,By,Bz, Cx,Cy,Cz);
            acc1 += pair2_direct(mqx1, mqy1, mqz1, Ax,Ay,Az, Bx,By,Bz, Cx,Cy,Cz);
        }

        // Write staged tile to the other buffer, then one barrier per tile.
        if (t + 1 < NT) {
            float* nb = lds + (cur ^ 1) * TILE_DW;
            #pragma unroll
            for (int k = 0; k < TILE_DW / 256; ++k) {
                const int d  = tid + k * 256;
                const int k2 = d - (d / PDW) * PDW;
                if (k2 < 18) nb[d] = stg[k];
            }
        }
        __syncthreads();
    }

    // Per-query wave reduction (each query owned by exactly one wave).
    float s0 = acc0.x + acc0.y;
    float s1 = acc1.x + acc1.y;
    #pragma unroll
    for (int m = 1; m < 64; m <<= 1) {
        s0 += __shfl_xor(s0, m);
        s1 += __shfl_xor(s1, m);
    }
    if (lane == 0) out[qbase + 0] = s0 * INV_2PI;
    if (lane == 1) out[qbase + 1] = s1 * INV_2PI;
}

extern "C" void kernel_launch(void* const* d_in, const int* in_sizes, int n_in,
                              void* d_out, int out_size, void* d_ws, size_t ws_size,
                              hipStream_t stream) {
    const float* qp = (const float*)d_in[0];   // query_points (1,4096,3) f32
    const float* fc = (const float*)d_in[1];   // face_coord   (1,4096,3,3) f32
    float* out = (float*)d_out;                // (1,4096) f32

    // Single dispatch; every out[q] is written exactly once (no memset,
    // no atomics, no workspace).
    winding_kernel<<<dim3(NBLK), dim3(256), 0, stream>>>(qp, fc, out);
}

// Round 13
// 29.101 us; speedup vs baseline: 1.2422x; 1.2422x over previous
//
#include <hip/hip_runtime.h>
#include <math.h>

// B=1, N=4096 queries, F=4096 faces (fixed by reference setup_inputs).
#define N_Q 4096
#define N_F 4096
#define QPT 2                  // queries per thread
#define QBLK (256 * QPT)       // 512 queries per block
#define FSPLIT 128             // 8 q-blocks x 128 f-splits = 1024 blocks (4/CU)
#define FT (N_F / FSPLIT)      // 32 faces per block
#define INV_2PI 0.15915494309189535f

// Fast atan2: 6-coeff odd minimax poly on [0,1] (max err ~1e-5 rad).
__device__ __forceinline__ float fast_atan2f(float y, float x) {
    const float pi   = 3.14159265358979f;
    const float pi_2 = 1.57079632679490f;
    float ax = fabsf(x), ay = fabsf(y);
    float mx = fmaxf(ax, ay), mn = fminf(ax, ay);
    mx = fmaxf(mx, 1e-30f);                        // 0/0 -> 0, no NaN
    float t = mn * __builtin_amdgcn_rcpf(mx);      // t in [0,1]
    float s = t * t;
    float p =              -0.0117212f;
    p = fmaf(p, s,  0.05265332f);
    p = fmaf(p, s, -0.11643287f);
    p = fmaf(p, s,  0.19354346f);
    p = fmaf(p, s, -0.33262347f);
    p = fmaf(p, s,  0.99997726f);
    float r = p * t;                               // atan(t) on [0, pi/4]
    r = (ay > ax) ? (pi_2 - r) : r;
    r = (x < 0.0f) ? (pi - r) : r;
    return copysignf(r, y);
}

// Angle-merge: atan2(y1,x1)+atan2(y2,x2) = atan2(ym,xm) + 2*pi*k.
// Exact wrap k: both y>0 & ym<0 -> +1 ; both y<0 & ym>0 -> -1.
// (theta_i in (-pi,pi], sign(theta)=sign(y); wrap iff |sum|>pi.)
__device__ __forceinline__ void merge_angle(
    float y1, float x1, float y2, float x2,
    float& ym, float& xm, float& w)
{
    ym = fmaf(y1, x2, y2 * x1);
    xm = fmaf(-y1, y2, x1 * x2);
    const float c = copysignf(1.0f, y1) + copysignf(1.0f, y2);  // +-2 or 0
    w += (ym * c < 0.0f) ? 0.5f * c : 0.0f;                     // +-1 wrap
}

// (det, denom) for one query/face from precomputed constants.
// d'_x = th - q.x ; |x-q|^2 = Px + 2 d'_x ; (x-q).(y-q) = Kxy + d'_x + d'_y
// det = D - q.n  with n = bxc + cxa + axb.
__device__ __forceinline__ void build_dn(
    float qx, float qy, float qz, float th,
    float4 A, float4 B, float4 C, float4 Nv, float4 K,
    float& det, float& den)
{
    const float da = fmaf(-qx, A.x, fmaf(-qy, A.y, fmaf(-qz, A.z, th)));
    const float db = fmaf(-qx, B.x, fmaf(-qy, B.y, fmaf(-qz, B.z, th)));
    const float dc = fmaf(-qx, C.x, fmaf(-qy, C.y, fmaf(-qz, C.z, th)));
    det = fmaf(-qx, Nv.x, fmaf(-qy, Nv.y, fmaf(-qz, Nv.z, Nv.w)));

    const float na = __builtin_amdgcn_sqrtf(fmaf(2.0f, da, A.w));
    const float nb = __builtin_amdgcn_sqrtf(fmaf(2.0f, db, B.w));
    const float nc = __builtin_amdgcn_sqrtf(fmaf(2.0f, dc, C.w));

    const float ab = K.x + (da + db);
    const float bc = K.y + (db + dc);
    const float ac = K.z + (da + dc);

    den = fmaf(na * nb, nc, fmaf(bc, na, fmaf(ac, nb, ab * nc)));
}

// Single dispatch (proven R6 structure): stage faces, build per-face
// constants in LDS; main loop processes faces in groups of 4, tree-merging
// the 4 (det,den) pairs into ONE atan2 with exact 2*pi-wrap tracking.
__global__ __launch_bounds__(256) void winding_kernel(
    const float* __restrict__ qp,   // [N_Q][3]
    const float* __restrict__ fc,   // [N_F][9]
    float* __restrict__ out)        // [N_Q]
{
    __shared__ float  raw[FT * 9];      // staged raw face data
    __shared__ float4 cst[FT][5];       // per-face constants

    const int tid = threadIdx.x;

    // Stage this block's face slice: FT*9 = 288 dwords = 72 float4s.
    {
        const float4* src = (const float4*)(fc + (size_t)blockIdx.y * FT * 9);
        float4* dst = (float4*)raw;
        if (tid < FT * 9 / 4) dst[tid] = src[tid];
    }
    __syncthreads();

    // Threads 0..FT-1: one face's constants each.
    // cst[f][0]=(a,|a|^2) [1]=(b,|b|^2) [2]=(c,|c|^2) [3]=(n,D) [4]=(a.b,b.c,a.c,0)
    if (tid < FT) {
        const float* v = &raw[tid * 9];
        const float ax = v[0], ay = v[1], az = v[2];
        const float bx = v[3], by = v[4], bz = v[5];
        const float cx = v[6], cy = v[7], cz = v[8];
        const float ux = by*cz - bz*cy, uy = bz*cx - bx*cz, uz = bx*cy - by*cx; // bxc
        const float vx = cy*az - cz*ay, vy = cz*ax - cx*az, vz = cx*ay - cy*ax; // cxa
        const float wx = ay*bz - az*by, wy = az*bx - ax*bz, wz = ax*by - ay*bx; // axb
        const float D  = ax*ux + ay*uy + az*uz;
        cst[tid][0] = make_float4(ax, ay, az, ax*ax + ay*ay + az*az);
        cst[tid][1] = make_float4(bx, by, bz, bx*bx + by*by + bz*bz);
        cst[tid][2] = make_float4(cx, cy, cz, cx*cx + cy*cy + cz*cz);
        cst[tid][3] = make_float4(ux + vx + wx, uy + vy + wy, uz + vz + wz, D);
        cst[tid][4] = make_float4(ax*bx + ay*by + az*bz,
                                  bx*cx + by*cy + bz*cz,
                                  ax*cx + ay*cy + az*cz, 0.0f);
    }
    __syncthreads();

    const int q0 = blockIdx.x * QBLK + tid;
    const int q1 = q0 + 256;
    const float q0x = qp[q0*3+0], q0y = qp[q0*3+1], q0z = qp[q0*3+2];
    const float q1x = qp[q1*3+0], q1y = qp[q1*3+1], q1z = qp[q1*3+2];
    const float th0 = 0.5f * fmaf(q0x, q0x, fmaf(q0y, q0y, q0z * q0z));
    const float th1 = 0.5f * fmaf(q1x, q1x, fmaf(q1y, q1y, q1z * q1z));

    float s0 = 0.0f, w0 = 0.0f;   // angle sum (rad) + wrap count (x 2*pi)
    float s1 = 0.0f, w1 = 0.0f;

    for (int f = 0; f < FT; f += 4) {
        // Broadcast (uniform-address) LDS reads, conflict-free.
        const float4 A0 = cst[f+0][0], B0 = cst[f+0][1], C0 = cst[f+0][2], N0 = cst[f+0][3], K0 = cst[f+0][4];
        const float4 A1 = cst[f+1][0], B1 = cst[f+1][1], C1 = cst[f+1][2], N1 = cst[f+1][3], K1 = cst[f+1][4];
        const float4 A2 = cst[f+2][0], B2 = cst[f+2][1], C2 = cst[f+2][2], N2 = cst[f+2][3], K2 = cst[f+2][4];
        const float4 A3 = cst[f+3][0], B3 = cst[f+3][1], C3 = cst[f+3][2], N3 = cst[f+3][3], K3 = cst[f+3][4];

        // ---- query 0: 4 builds, 3 merges, 1 atan2 ----
        {
            float d0,n0,d1,n1,d2,n2,d3,n3;
            build_dn(q0x,q0y,q0z,th0, A0,B0,C0,N0,K0, d0,n0);
            build_dn(q0x,q0y,q0z,th0, A1,B1,C1,N1,K1, d1,n1);
            build_dn(q0x,q0y,q0z,th0, A2,B2,C2,N2,K2, d2,n2);
            build_dn(q0x,q0y,q0z,th0, A3,B3,C3,N3,K3, d3,n3);
            float ya,xa,yb,xb,Y,X;
            merge_angle(d0,n0, d1,n1, ya,xa, w0);
            merge_angle(d2,n2, d3,n3, yb,xb, w0);
            merge_angle(ya,xa, yb,xb, Y, X,  w0);
            s0 += fast_atan2f(Y, X);
        }
        // ---- query 1 ----
        {
            float d0,n0,d1,n1,d2,n2,d3,n3;
            build_dn(q1x,q1y,q1z,th1, A0,B0,C0,N0,K0, d0,n0);
            build_dn(q1x,q1y,q1z,th1, A1,B1,C1,N1,K1, d1,n1);
            build_dn(q1x,q1y,q1z,th1, A2,B2,C2,N2,K2, d2,n2);
            build_dn(q1x,q1y,q1z,th1, A3,B3,C3,N3,K3, d3,n3);
            float ya,xa,yb,xb,Y,X;
            merge_angle(d0,n0, d1,n1, ya,xa, w1);
            merge_angle(d2,n2, d3,n3, yb,xb, w1);
            merge_angle(ya,xa, yb,xb, Y, X,  w1);
            s1 += fast_atan2f(Y, X);
        }
    }

    // winding = (s + 2*pi*w) / (2*pi) = s/(2*pi) + w
    atomicAdd(&out[q0], fmaf(s0, INV_2PI, w0));
    atomicAdd(&out[q1], fmaf(s1, INV_2PI, w1));
}

extern "C" void kernel_launch(void* const* d_in, const int* in_sizes, int n_in,
                              void* d_out, int out_size, void* d_ws, size_t ws_size,
                              hipStream_t stream) {
    const float* qp = (const float*)d_in[0];   // query_points (1,4096,3) f32
    const float* fc = (const float*)d_in[1];   // face_coord   (1,4096,3,3) f32
    float* out = (float*)d_out;                // (1,4096) f32

    // Harness poisons d_out once and never re-poisons between replays:
    // we accumulate with atomics, so zero it ourselves every call.
    hipMemsetAsync(out, 0, (size_t)out_size * sizeof(float), stream);

    dim3 grid(N_Q / QBLK, FSPLIT);
    dim3 block(256);
    winding_kernel<<<grid, block, 0, stream>>>(qp, fc, out);
}